// Round 2
// baseline (362.734 us; speedup 1.0000x reference)
//
#include <hip/hip_runtime.h>
#include <cstdint>
#include <cstddef>

typedef unsigned short u16t;
typedef __attribute__((ext_vector_type(4))) float f32x4;
typedef __attribute__((ext_vector_type(8))) __bf16 bf16x8;
typedef __attribute__((ext_vector_type(8))) unsigned short u16x8;
typedef __attribute__((ext_vector_type(4))) unsigned short u16x4;

#define INFF __builtin_inff()

__device__ __forceinline__ u16t f2b(float f) {
  union { float f; unsigned u; } x; x.f = f;
  unsigned r = x.u + 0x7FFFu + ((x.u >> 16) & 1u);   // RNE
  return (u16t)(r >> 16);
}

// ---------------- fp32 -> bf16 convert (vectorized) ----------------
__global__ __launch_bounds__(256) void k_cvt(const float* __restrict__ s,
                                             u16t* __restrict__ d, int n4) {
  int i = blockIdx.x * 256 + threadIdx.x;
  if (i >= n4) return;
  f32x4 v = *(const f32x4*)(s + (size_t)i * 4);
  u16x4 o;
  o[0] = f2b(v[0]); o[1] = f2b(v[1]); o[2] = f2b(v[2]); o[3] = f2b(v[3]);
  *(u16x4*)(d + (size_t)i * 4) = o;
}

// ---------------- fp32 (R x C) -> bf16 transposed (C x R) ----------------
__global__ __launch_bounds__(256) void k_transpose_w(const float* __restrict__ src,
                                                     u16t* __restrict__ dst,
                                                     int R, int C) {
  __shared__ float tile[64 * 65];
  const int t = threadIdx.x;
  const int cb = blockIdx.x * 64, rb = blockIdx.y * 64;
#pragma unroll
  for (int it = 0; it < 4; ++it) {
    int c = it * 256 + t;
    int r = c >> 4, ch = c & 15;
    f32x4 v = *(const f32x4*)(src + (size_t)(rb + r) * C + cb + ch * 4);
    float* dp = &tile[r * 65 + ch * 4];
    dp[0] = v[0]; dp[1] = v[1]; dp[2] = v[2]; dp[3] = v[3];
  }
  __syncthreads();
#pragma unroll
  for (int it = 0; it < 2; ++it) {
    int c = it * 256 + t;
    int dr = c >> 3, ch = c & 7;
    u16x8 o;
#pragma unroll
    for (int i = 0; i < 8; ++i) o[i] = f2b(tile[(ch * 8 + i) * 65 + dr]);
    *(u16x8*)(dst + (size_t)(cb + dr) * R + rb + ch * 8) = o;
  }
}

// ---------------- v half of kv -> per-head transposed vT ----------------
// kv16: (8192, 2048) bf16, v half = cols [1024,2048).  vT: (b,h,64,4096)
__global__ __launch_bounds__(256) void k_transpose_v(const u16t* __restrict__ kv16,
                                                     u16t* __restrict__ vT) {
  __shared__ u16t tile[64 * 65];
  const int t = threadIdx.x;
  const int kvb = blockIdx.x * 64;
  const int h = blockIdx.y, b = blockIdx.z;
#pragma unroll
  for (int it = 0; it < 2; ++it) {
    int c = it * 256 + t;
    int r = c >> 3, ch = c & 7;
    u16x8 v = *(const u16x8*)(kv16 + (size_t)(b * 4096 + kvb + r) * 2048 + 1024 + h * 64 + ch * 8);
    u16t* dp = &tile[r * 65 + ch * 8];
#pragma unroll
    for (int i = 0; i < 8; ++i) dp[i] = v[i];
  }
  __syncthreads();
#pragma unroll
  for (int it = 0; it < 2; ++it) {
    int c = it * 256 + t;
    int dr = c >> 3, ch = c & 7;   // dr = hd index, ch*8.. = kv within tile
    u16x8 o;
#pragma unroll
    for (int i = 0; i < 8; ++i) o[i] = tile[(ch * 8 + i) * 65 + dr];
    *(u16x8*)(vT + ((size_t)(b * 16 + h) * 64 + dr) * 4096 + kvb + ch * 8) = o;
  }
}

// ---------------- bf16 GEMM: C(MxN) = A(MxK) @ Bt(NxK)^T ----------------
// 128x128 tile, BK=64, 4 waves (2x2), XOR-swizzled LDS.
template <int OUTF32, int BIAS>
__global__ __launch_bounds__(256) void k_gemm_bt(const u16t* __restrict__ A,
                                                 const u16t* __restrict__ Bt,
                                                 void* __restrict__ C,
                                                 const float* __restrict__ bias,
                                                 int K, int lda, int ldb, int ldc) {
  __shared__ u16t As[128 * 64];
  __shared__ u16t Bs[128 * 64];
  const int tid = threadIdx.x;
  const int lane = tid & 63, wid = tid >> 6;
  const int l16 = lane & 15, lg = lane >> 4;
  const int wr = wid >> 1, wc = wid & 1;
  const int brow = blockIdx.y * 128, bcol = blockIdx.x * 128;
  f32x4 acc[4][4] = {};

  for (int k0 = 0; k0 < K; k0 += 64) {
#pragma unroll
    for (int it = 0; it < 4; ++it) {
      int c = it * 256 + tid;
      int row = c >> 3, chs = c & 7, ch = chs ^ (row & 7);
      u16x8 va = *(const u16x8*)(A + (size_t)(brow + row) * lda + k0 + ch * 8);
      u16x8 vb = *(const u16x8*)(Bt + (size_t)(bcol + row) * ldb + k0 + ch * 8);
      *(u16x8*)(&As[row * 64 + chs * 8]) = va;
      *(u16x8*)(&Bs[row * 64 + chs * 8]) = vb;
    }
    __syncthreads();
#pragma unroll
    for (int kk = 0; kk < 2; ++kk) {
      bf16x8 af[4], bfv[4];
#pragma unroll
      for (int mi = 0; mi < 4; ++mi) {
        int row = wr * 64 + mi * 16 + l16;
        int kch = (kk * 4 + lg) ^ (row & 7);
        af[mi] = *(const bf16x8*)(&As[row * 64 + kch * 8]);
      }
#pragma unroll
      for (int ni = 0; ni < 4; ++ni) {
        int row = wc * 64 + ni * 16 + l16;
        int kch = (kk * 4 + lg) ^ (row & 7);
        bfv[ni] = *(const bf16x8*)(&Bs[row * 64 + kch * 8]);
      }
#pragma unroll
      for (int mi = 0; mi < 4; ++mi)
#pragma unroll
        for (int ni = 0; ni < 4; ++ni)
          acc[mi][ni] = __builtin_amdgcn_mfma_f32_16x16x32_bf16(af[mi], bfv[ni], acc[mi][ni], 0, 0, 0);
    }
    __syncthreads();
  }
#pragma unroll
  for (int mi = 0; mi < 4; ++mi) {
#pragma unroll
    for (int ni = 0; ni < 4; ++ni) {
#pragma unroll
      for (int j = 0; j < 4; ++j) {
        size_t row = (size_t)brow + wr * 64 + mi * 16 + lg * 4 + j;
        int col = bcol + wc * 64 + ni * 16 + l16;
        float v = acc[mi][ni][j];
        if (BIAS) v += bias[col];
        if (OUTF32)
          ((float*)C)[row * ldc + col] = v;
        else
          ((u16t*)C)[row * ldc + col] = f2b(v);
      }
    }
  }
}

// ---------------- fused attention ----------------
// grid (16 n-tiles, 16 heads, 2 batch); 4 waves x 16 q-rows each; kv tiles of 128.
__global__ __launch_bounds__(256) void k_attn(const u16t* __restrict__ q16,
                                              const u16t* __restrict__ kv16,
                                              const u16t* __restrict__ vT16,
                                              const float* __restrict__ dsim,
                                              const int* __restrict__ mask,
                                              const int* __restrict__ cmask,
                                              const float* __restrict__ beta_p,
                                              float* __restrict__ pre,
                                              u16t* __restrict__ O16) {
  __shared__ u16t Ks[128 * 64];      // [kv 128][hd 64] swizzled
  __shared__ u16t Vs[64 * 128];      // [hd 64][kv 128] swizzled
  __shared__ u16t Ps[4 * 16 * 128];  // per-wave P tile, swizzled

  const int tid = threadIdx.x;
  const int lane = tid & 63, wid = tid >> 6;
  const int l16 = lane & 15, lg = lane >> 4;
  const int nb = blockIdx.x, h = blockIdx.y, b = blockIdx.z;
  const float beta = beta_p[0];
  const int qrow0 = nb * 64 + wid * 16;

  bf16x8 aq0, aq1;
  {
    const u16t* qp = q16 + (size_t)(b * 1024 + qrow0 + l16) * 1024 + h * 64 + lg * 8;
    aq0 = *(const bf16x8*)(qp);
    aq1 = *(const bf16x8*)(qp + 32);
  }
  bool qm[4];
#pragma unroll
  for (int j = 0; j < 4; ++j) qm[j] = mask[b * 1024 + qrow0 + lg * 4 + j] != 0;

  const float ds0 = dsim[b * 4 + 0] * beta, ds1 = dsim[b * 4 + 1] * beta;
  const float ds2 = dsim[b * 4 + 2] * beta, ds3 = dsim[b * 4 + 3] * beta;

  float mrow[4], lsum[4];
#pragma unroll
  for (int j = 0; j < 4; ++j) { mrow[j] = -INFF; lsum[j] = 0.f; }
  f32x4 o[4] = {};

  const u16t* kbase = kv16 + (size_t)b * 4096 * 2048 + (size_t)h * 64;
  const u16t* vbase = vT16 + (size_t)(b * 16 + h) * 64 * 4096;
  float* prebase = pre + (size_t)((b * 16 + h) * 1024 + qrow0) * 4096;
  const int* cmb = cmask + b * 4096;
  u16t* Pw = &Ps[wid * 2048];

  for (int kv0 = 0; kv0 < 4096; kv0 += 128) {
    // stage K (128x64) and V^T (64x128) tiles, XOR-swizzled
#pragma unroll
    for (int it = 0; it < 4; ++it) {
      int c = it * 256 + tid;
      {
        int row = c >> 3, chs = c & 7, ch = chs ^ (row & 7);
        u16x8 v = *(const u16x8*)(kbase + (size_t)(kv0 + row) * 2048 + ch * 8);
        *(u16x8*)(&Ks[row * 64 + chs * 8]) = v;
      }
      {
        int row = c >> 4, chs = c & 15, ch = chs ^ (row & 7);
        u16x8 v = *(const u16x8*)(vbase + (size_t)row * 4096 + kv0 + ch * 8);
        *(u16x8*)(&Vs[row * 128 + chs * 8]) = v;
      }
    }
    __syncthreads();

    // S = q @ k^T  (8 col-frags x 2 k-steps)
    f32x4 s[8];
#pragma unroll
    for (int kb = 0; kb < 8; ++kb) {
      f32x4 acc = {0.f, 0.f, 0.f, 0.f};
      int row = kb * 16 + l16;
      bf16x8 bk0 = *(const bf16x8*)(&Ks[row * 64 + ((lg ^ (row & 7)) << 3)]);
      bf16x8 bk1 = *(const bf16x8*)(&Ks[row * 64 + (((4 + lg) ^ (row & 7)) << 3)]);
      acc = __builtin_amdgcn_mfma_f32_16x16x32_bf16(aq0, bk0, acc, 0, 0, 0);
      acc = __builtin_amdgcn_mfma_f32_16x16x32_bf16(aq1, bk1, acc, 0, 0, 0);
      s[kb] = acc;
    }

    // scale, store pre, ds bias + faithful mask, row-max
    float tmax[4] = {-INFF, -INFF, -INFF, -INFF};
#pragma unroll
    for (int kb = 0; kb < 8; ++kb) {
      int col = kv0 + kb * 16 + l16;
      bool km = cmb[col] != 0;
      float ds = (col < 2048) ? (col < 1024 ? ds0 : ds1) : (col < 3072 ? ds2 : ds3);
#pragma unroll
      for (int j = 0; j < 4; ++j) {
        float sv = s[kb][j] * 0.03125f;  // * d^-0.5
        prebase[(size_t)(lg * 4 + j) * 4096 + col] = sv;
        float t = sv + ds;
        if (!(qm[j] && km)) t = 0.f;
        if (t == 0.f) t = -INFF;
        s[kb][j] = t;
        tmax[j] = fmaxf(tmax[j], t);
      }
    }
#pragma unroll
    for (int off = 1; off < 16; off <<= 1) {
#pragma unroll
      for (int j = 0; j < 4; ++j) tmax[j] = fmaxf(tmax[j], __shfl_xor(tmax[j], off, 64));
    }
    float fs[4], psum[4];
#pragma unroll
    for (int j = 0; j < 4; ++j) {
      float mn = fmaxf(mrow[j], tmax[j]);
      fs[j] = (mn == -INFF) ? 0.f : __expf(mrow[j] - mn);
      mrow[j] = mn;
      psum[j] = 0.f;
    }
    // P = exp(t - m), write to per-wave LDS (C-layout -> A-layout bounce)
#pragma unroll
    for (int kb = 0; kb < 8; ++kb) {
#pragma unroll
      for (int j = 0; j < 4; ++j) {
        float p = (mrow[j] == -INFF) ? 0.f : __expf(s[kb][j] - mrow[j]);
        psum[j] += p;
        int lrow = lg * 4 + j;
        int off = (lrow * 256 + (kb * 16 + l16) * 2) ^ ((lrow & 7) << 4);
        *(u16t*)((char*)Pw + off) = f2b(p);
      }
    }
    asm volatile("" ::: "memory");  // keep P writes ordered before P reads
#pragma unroll
    for (int off = 1; off < 16; off <<= 1) {
#pragma unroll
      for (int j = 0; j < 4; ++j) psum[j] += __shfl_xor(psum[j], off, 64);
    }
#pragma unroll
    for (int j = 0; j < 4; ++j) lsum[j] = lsum[j] * fs[j] + psum[j];
#pragma unroll
    for (int ni = 0; ni < 4; ++ni)
#pragma unroll
      for (int j = 0; j < 4; ++j) o[ni][j] *= fs[j];

    // O += P @ V
#pragma unroll
    for (int kk2 = 0; kk2 < 4; ++kk2) {
      int pch = (kk2 * 4 + lg) ^ (l16 & 7);
      bf16x8 pa = *(const bf16x8*)((const char*)Pw + l16 * 256 + (pch << 4));
#pragma unroll
      for (int ni = 0; ni < 4; ++ni) {
        int vrow = ni * 16 + l16;
        bf16x8 vb = *(const bf16x8*)(&Vs[vrow * 128 + (((kk2 * 4 + lg) ^ (vrow & 7)) << 3)]);
        o[ni] = __builtin_amdgcn_mfma_f32_16x16x32_bf16(pa, vb, o[ni], 0, 0, 0);
      }
    }
    __syncthreads();
  }

#pragma unroll
  for (int ni = 0; ni < 4; ++ni) {
#pragma unroll
    for (int j = 0; j < 4; ++j) {
      size_t row = (size_t)b * 1024 + qrow0 + lg * 4 + j;
      int col = h * 64 + ni * 16 + l16;
      O16[row * 1024 + col] = f2b(o[ni][j] / lsum[j]);
    }
  }
}

extern "C" void kernel_launch(void* const* d_in, const int* in_sizes, int n_in,
                              void* d_out, int out_size, void* d_ws, size_t ws_size,
                              hipStream_t stream) {
  const float* x = (const float*)d_in[0];
  const float* ctx = (const float*)d_in[1];
  const float* dsim = (const float*)d_in[2];
  const int* mask = (const int*)d_in[3];
  const int* cmask = (const int*)d_in[4];
  const float* Wq = (const float*)d_in[5];
  const float* Wkv = (const float*)d_in[6];
  const float* Wout = (const float*)d_in[7];
  const float* bout = (const float*)d_in[8];
  const float* beta = (const float*)d_in[9];

  char* ws = (char*)d_ws;
  u16t* q16 = (u16t*)(ws + (0ull << 20));     //  4 MiB (2048x1024)
  u16t* kv16 = (u16t*)(ws + (4ull << 20));    // 32 MiB (8192x2048)
  u16t* vT16 = (u16t*)(ws + (36ull << 20));   // 16 MiB (2,16,64,4096)
  u16t* O16 = (u16t*)(ws + (52ull << 20));    //  4 MiB (2048x1024)
  u16t* x16 = (u16t*)(ws + (56ull << 20));    //  4 MiB
  u16t* ctx16 = (u16t*)(ws + (60ull << 20));  // 16 MiB
  u16t* WqT = (u16t*)(ws + (76ull << 20));    //  2 MiB (1024x1024 T)
  u16t* WkvT = (u16t*)(ws + (78ull << 20));   //  4 MiB (2048x1024 T)
  u16t* WoutT = (u16t*)(ws + (82ull << 20));  //  2 MiB

  float* outp = (float*)d_out;
  float* pre = outp + (size_t)2 * 1024 * 1024;

  k_cvt<<<2048, 256, 0, stream>>>(x, x16, 524288);
  k_cvt<<<8192, 256, 0, stream>>>(ctx, ctx16, 2097152);
  k_transpose_w<<<dim3(16, 16), 256, 0, stream>>>(Wq, WqT, 1024, 1024);
  k_transpose_w<<<dim3(32, 16), 256, 0, stream>>>(Wkv, WkvT, 1024, 2048);
  k_transpose_w<<<dim3(16, 16), 256, 0, stream>>>(Wout, WoutT, 1024, 1024);

  // q = x @ Wq   (2048x1024) bf16
  k_gemm_bt<0, 0><<<dim3(8, 16), 256, 0, stream>>>(x16, WqT, (void*)q16, nullptr, 1024, 1024, 1024, 1024);
  // kv = ctx @ Wkv (8192x2048) bf16
  k_gemm_bt<0, 0><<<dim3(16, 64), 256, 0, stream>>>(ctx16, WkvT, (void*)kv16, nullptr, 1024, 1024, 1024, 2048);
  // v -> per-head transposed
  k_transpose_v<<<dim3(64, 16, 2), 256, 0, stream>>>(kv16, vT16);
  // fused QK^T + pre-store + softmax + PV
  k_attn<<<dim3(16, 16, 2), 256, 0, stream>>>(q16, kv16, vT16, dsim, mask, cmask, beta, pre, O16);
  // out = O @ Wout + bout  (f32)
  k_gemm_bt<1, 1><<<dim3(8, 16), 256, 0, stream>>>(O16, WoutT, d_out, bout, 1024, 1024, 1024, 1024);
}

// Round 3
// 302.828 us; speedup vs baseline: 1.1978x; 1.1978x over previous
//
#include <hip/hip_runtime.h>
#include <cstdint>
#include <cstddef>

typedef unsigned short u16t;
typedef __attribute__((ext_vector_type(4))) float f32x4;
typedef __attribute__((ext_vector_type(8))) __bf16 bf16x8;
typedef __attribute__((ext_vector_type(8))) unsigned short u16x8;
typedef __attribute__((ext_vector_type(4))) unsigned short u16x4;

#define INFF __builtin_inff()

__device__ __forceinline__ u16t f2b(float f) {
  union { float f; unsigned u; } x; x.f = f;
  unsigned r = x.u + 0x7FFFu + ((x.u >> 16) & 1u);   // RNE
  return (u16t)(r >> 16);
}

// async global->LDS, 16B per lane. LDS dest = wave-uniform base + lane*16.
__device__ __forceinline__ void gload16(const u16t* g, u16t* l) {
  __builtin_amdgcn_global_load_lds((const __attribute__((address_space(1))) void*)g,
                                   (__attribute__((address_space(3))) void*)l, 16, 0, 0);
}

// ---------------- fp32 -> bf16 convert (vectorized) ----------------
__global__ __launch_bounds__(256) void k_cvt(const float* __restrict__ s,
                                             u16t* __restrict__ d, int n4) {
  int i = blockIdx.x * 256 + threadIdx.x;
  if (i >= n4) return;
  f32x4 v = *(const f32x4*)(s + (size_t)i * 4);
  u16x4 o;
  o[0] = f2b(v[0]); o[1] = f2b(v[1]); o[2] = f2b(v[2]); o[3] = f2b(v[3]);
  *(u16x4*)(d + (size_t)i * 4) = o;
}

// ---------------- fp32 (R x C) -> bf16 transposed (C x R) ----------------
__global__ __launch_bounds__(256) void k_transpose_w(const float* __restrict__ src,
                                                     u16t* __restrict__ dst,
                                                     int R, int C) {
  __shared__ float tile[64 * 65];
  const int t = threadIdx.x;
  const int cb = blockIdx.x * 64, rb = blockIdx.y * 64;
#pragma unroll
  for (int it = 0; it < 4; ++it) {
    int c = it * 256 + t;
    int r = c >> 4, ch = c & 15;
    f32x4 v = *(const f32x4*)(src + (size_t)(rb + r) * C + cb + ch * 4);
    float* dp = &tile[r * 65 + ch * 4];
    dp[0] = v[0]; dp[1] = v[1]; dp[2] = v[2]; dp[3] = v[3];
  }
  __syncthreads();
#pragma unroll
  for (int it = 0; it < 2; ++it) {
    int c = it * 256 + t;
    int dr = c >> 3, ch = c & 7;
    u16x8 o;
#pragma unroll
    for (int i = 0; i < 8; ++i) o[i] = f2b(tile[(ch * 8 + i) * 65 + dr]);
    *(u16x8*)(dst + (size_t)(cb + dr) * R + rb + ch * 8) = o;
  }
}

// ---------------- v half of kv -> per-head transposed vT ----------------
__global__ __launch_bounds__(256) void k_transpose_v(const u16t* __restrict__ kv16,
                                                     u16t* __restrict__ vT) {
  __shared__ u16t tile[64 * 65];
  const int t = threadIdx.x;
  const int kvb = blockIdx.x * 64;
  const int h = blockIdx.y, b = blockIdx.z;
#pragma unroll
  for (int it = 0; it < 2; ++it) {
    int c = it * 256 + t;
    int r = c >> 3, ch = c & 7;
    u16x8 v = *(const u16x8*)(kv16 + (size_t)(b * 4096 + kvb + r) * 2048 + 1024 + h * 64 + ch * 8);
    u16t* dp = &tile[r * 65 + ch * 8];
#pragma unroll
    for (int i = 0; i < 8; ++i) dp[i] = v[i];
  }
  __syncthreads();
#pragma unroll
  for (int it = 0; it < 2; ++it) {
    int c = it * 256 + t;
    int dr = c >> 3, ch = c & 7;
    u16x8 o;
#pragma unroll
    for (int i = 0; i < 8; ++i) o[i] = tile[(ch * 8 + i) * 65 + dr];
    *(u16x8*)(vT + ((size_t)(b * 16 + h) * 64 + dr) * 4096 + kvb + ch * 8) = o;
  }
}

// ---------------- bf16 GEMM: C(MxN) = A(MxK) @ Bt(NxK)^T ----------------
// 128x128 tile, BK=64, 4 waves, global_load_lds staging (m97 structure),
// XOR swizzle applied on the per-lane GLOBAL source address (LDS dest linear).
template <int OUTF32, int BIAS>
__global__ __launch_bounds__(256) void k_gemm_bt(const u16t* __restrict__ A,
                                                 const u16t* __restrict__ Bt,
                                                 void* __restrict__ C,
                                                 const float* __restrict__ bias,
                                                 int K, int lda, int ldb, int ldc, int nbx) {
  __shared__ u16t As[128 * 64];
  __shared__ u16t Bs[128 * 64];
  const int tid = threadIdx.x;
  const int lane = tid & 63, wid = tid >> 6;
  const int l16 = lane & 15, lg = lane >> 4;
  const int wr = wid >> 1, wc = wid & 1;
  // XCD-aware bijective swizzle (gridDim.x divisible by 8)
  const int g = blockIdx.x, per = gridDim.x >> 3;
  const int w = (g & 7) * per + (g >> 3);
  const int bx = w % nbx, by = w / nbx;
  const int brow = by * 128, bcol = bx * 128;
  const int sr = lane >> 3, chs = lane & 7;
  f32x4 acc[4][4] = {};

  for (int k0 = 0; k0 < K; k0 += 64) {
#pragma unroll
    for (int it = 0; it < 4; ++it) {
      int row = it * 32 + wid * 8 + sr;
      int ch = chs ^ (row & 7);
      gload16(A + (size_t)(brow + row) * lda + k0 + ch * 8, &As[it * 2048 + wid * 512]);
      gload16(Bt + (size_t)(bcol + row) * ldb + k0 + ch * 8, &Bs[it * 2048 + wid * 512]);
    }
    __syncthreads();
#pragma unroll
    for (int kk = 0; kk < 2; ++kk) {
      bf16x8 af[4], bfv[4];
#pragma unroll
      for (int mi = 0; mi < 4; ++mi) {
        int row = wr * 64 + mi * 16 + l16;
        int kch = (kk * 4 + lg) ^ (row & 7);
        af[mi] = *(const bf16x8*)(&As[row * 64 + kch * 8]);
      }
#pragma unroll
      for (int ni = 0; ni < 4; ++ni) {
        int row = wc * 64 + ni * 16 + l16;
        int kch = (kk * 4 + lg) ^ (row & 7);
        bfv[ni] = *(const bf16x8*)(&Bs[row * 64 + kch * 8]);
      }
#pragma unroll
      for (int mi = 0; mi < 4; ++mi)
#pragma unroll
        for (int ni = 0; ni < 4; ++ni)
          acc[mi][ni] = __builtin_amdgcn_mfma_f32_16x16x32_bf16(af[mi], bfv[ni], acc[mi][ni], 0, 0, 0);
    }
    __syncthreads();
  }
#pragma unroll
  for (int mi = 0; mi < 4; ++mi) {
#pragma unroll
    for (int ni = 0; ni < 4; ++ni) {
#pragma unroll
      for (int j = 0; j < 4; ++j) {
        size_t row = (size_t)brow + wr * 64 + mi * 16 + lg * 4 + j;
        int col = bcol + wc * 64 + ni * 16 + l16;
        float v = acc[mi][ni][j];
        if (BIAS) v += bias[col];
        if (OUTF32)
          __builtin_nontemporal_store(v, (float*)C + row * ldc + col);
        else
          ((u16t*)C)[row * ldc + col] = f2b(v);
      }
    }
  }
}

// ---------------- fused attention ----------------
// 1-D grid 512, XCD-grouped so 16 n-blocks sharing (b,h) K/V land on one XCD.
// K/V double-buffered via global_load_lds; prefetch issued before compute.
__global__ __launch_bounds__(256) void k_attn(const u16t* __restrict__ q16,
                                              const u16t* __restrict__ kv16,
                                              const u16t* __restrict__ vT16,
                                              const float* __restrict__ dsim,
                                              const int* __restrict__ mask,
                                              const int* __restrict__ cmask,
                                              const float* __restrict__ beta_p,
                                              float* __restrict__ pre,
                                              u16t* __restrict__ O16) {
  __shared__ u16t Ks[2][128 * 64];   // [kv 128][hd 64] swizzled
  __shared__ u16t Vs[2][64 * 128];   // [hd 64][kv 128] swizzled
  __shared__ u16t Ps[4 * 16 * 128];  // per-wave P tile, swizzled

  const int tid = threadIdx.x;
  const int lane = tid & 63, wid = tid >> 6;
  const int l16 = lane & 15, lg = lane >> 4;
  // XCD swizzle: w = (g%8)*64 + g/8 ; nb fastest so same (b,h) groups stay on one XCD
  const int g = blockIdx.x;
  const int w = (g & 7) * 64 + (g >> 3);
  const int nb = w & 15, hb = w >> 4;
  const int h = hb & 15, b = hb >> 4;
  const float beta = beta_p[0];
  const int qrow0 = nb * 64 + wid * 16;

  bf16x8 aq0, aq1;
  {
    const u16t* qp = q16 + (size_t)(b * 1024 + qrow0 + l16) * 1024 + h * 64 + lg * 8;
    aq0 = *(const bf16x8*)(qp);
    aq1 = *(const bf16x8*)(qp + 32);
  }
  bool qm[4];
#pragma unroll
  for (int j = 0; j < 4; ++j) qm[j] = mask[b * 1024 + qrow0 + lg * 4 + j] != 0;

  const float ds0 = dsim[b * 4 + 0] * beta, ds1 = dsim[b * 4 + 1] * beta;
  const float ds2 = dsim[b * 4 + 2] * beta, ds3 = dsim[b * 4 + 3] * beta;

  float mrow[4], lsum[4];
#pragma unroll
  for (int j = 0; j < 4; ++j) { mrow[j] = -INFF; lsum[j] = 0.f; }
  f32x4 o[4] = {};

  const u16t* kbase = kv16 + (size_t)b * 4096 * 2048 + (size_t)h * 64;
  const u16t* vbase = vT16 + (size_t)(b * 16 + h) * 64 * 4096;
  float* prebase = pre + (size_t)((b * 16 + h) * 1024 + qrow0) * 4096;
  const int* cmb = cmask + b * 4096;
  u16t* Pw = &Ps[wid * 2048];

  auto stage = [&](int bufi, int kv0s) {
    u16t* Kb = &Ks[bufi][wid * 2048];
    u16t* Vb = &Vs[bufi][wid * 2048];
#pragma unroll
    for (int it = 0; it < 4; ++it) {
      int row = wid * 32 + it * 8 + (lane >> 3);
      int ch = (lane & 7) ^ (row & 7);
      gload16(kbase + (size_t)(kv0s + row) * 2048 + ch * 8, Kb + it * 512);
    }
#pragma unroll
    for (int it = 0; it < 4; ++it) {
      int row = wid * 16 + it * 4 + (lane >> 4);
      int ch = (lane & 15) ^ (row & 7);
      gload16(vbase + (size_t)row * 4096 + kv0s + ch * 8, Vb + it * 512);
    }
  };

  int cur = 0;
  stage(0, 0);
  __syncthreads();

  for (int t = 0; t < 32; ++t) {
    if (t + 1 < 32) stage(cur ^ 1, (t + 1) * 128);  // prefetch overlaps compute
    const u16t* Kc = &Ks[cur][0];
    const u16t* Vc = &Vs[cur][0];
    const int kv0 = t * 128;

    // S = q @ k^T
    f32x4 s[8];
#pragma unroll
    for (int kb = 0; kb < 8; ++kb) {
      f32x4 acc = {0.f, 0.f, 0.f, 0.f};
      int row = kb * 16 + l16;
      bf16x8 bk0 = *(const bf16x8*)(&Kc[row * 64 + ((lg ^ (row & 7)) << 3)]);
      bf16x8 bk1 = *(const bf16x8*)(&Kc[row * 64 + (((4 + lg) ^ (row & 7)) << 3)]);
      acc = __builtin_amdgcn_mfma_f32_16x16x32_bf16(aq0, bk0, acc, 0, 0, 0);
      acc = __builtin_amdgcn_mfma_f32_16x16x32_bf16(aq1, bk1, acc, 0, 0, 0);
      s[kb] = acc;
    }

    // scale, store pre (non-temporal), ds bias + faithful mask, row-max
    float tmax[4] = {-INFF, -INFF, -INFF, -INFF};
#pragma unroll
    for (int kb = 0; kb < 8; ++kb) {
      int col = kv0 + kb * 16 + l16;
      bool km = cmb[col] != 0;
      float ds = (col < 2048) ? (col < 1024 ? ds0 : ds1) : (col < 3072 ? ds2 : ds3);
#pragma unroll
      for (int j = 0; j < 4; ++j) {
        float sv = s[kb][j] * 0.03125f;  // * d^-0.5
        __builtin_nontemporal_store(sv, prebase + (size_t)(lg * 4 + j) * 4096 + col);
        float t2 = sv + ds;
        if (!(qm[j] && km)) t2 = 0.f;
        if (t2 == 0.f) t2 = -INFF;
        s[kb][j] = t2;
        tmax[j] = fmaxf(tmax[j], t2);
      }
    }
#pragma unroll
    for (int off = 1; off < 16; off <<= 1) {
#pragma unroll
      for (int j = 0; j < 4; ++j) tmax[j] = fmaxf(tmax[j], __shfl_xor(tmax[j], off, 64));
    }
    float fs[4], psum[4];
#pragma unroll
    for (int j = 0; j < 4; ++j) {
      float mn = fmaxf(mrow[j], tmax[j]);
      fs[j] = (mn == -INFF) ? 0.f : __expf(mrow[j] - mn);
      mrow[j] = mn;
      psum[j] = 0.f;
    }
    // P = exp(t - m) -> per-wave LDS bounce (C-layout -> A-layout)
#pragma unroll
    for (int kb = 0; kb < 8; ++kb) {
#pragma unroll
      for (int j = 0; j < 4; ++j) {
        float p = (mrow[j] == -INFF) ? 0.f : __expf(s[kb][j] - mrow[j]);
        psum[j] += p;
        int lrow = lg * 4 + j;
        int off = (lrow * 256 + (kb * 16 + l16) * 2) ^ ((lrow & 7) << 4);
        *(u16t*)((char*)Pw + off) = f2b(p);
      }
    }
    asm volatile("" ::: "memory");
#pragma unroll
    for (int off = 1; off < 16; off <<= 1) {
#pragma unroll
      for (int j = 0; j < 4; ++j) psum[j] += __shfl_xor(psum[j], off, 64);
    }
#pragma unroll
    for (int j = 0; j < 4; ++j) lsum[j] = lsum[j] * fs[j] + psum[j];
#pragma unroll
    for (int ni = 0; ni < 4; ++ni)
#pragma unroll
      for (int j = 0; j < 4; ++j) o[ni][j] *= fs[j];

    // O += P @ V
#pragma unroll
    for (int kk2 = 0; kk2 < 4; ++kk2) {
      int pch = (kk2 * 4 + lg) ^ (l16 & 7);
      bf16x8 pa = *(const bf16x8*)((const char*)Pw + l16 * 256 + (pch << 4));
#pragma unroll
      for (int ni = 0; ni < 4; ++ni) {
        int vrow = ni * 16 + l16;
        bf16x8 vb = *(const bf16x8*)(&Vc[vrow * 128 + (((kk2 * 4 + lg) ^ (vrow & 7)) << 3)]);
        o[ni] = __builtin_amdgcn_mfma_f32_16x16x32_bf16(pa, vb, o[ni], 0, 0, 0);
      }
    }
    __syncthreads();  // drains prefetch vmcnt + protects buffer swap
    cur ^= 1;
  }

#pragma unroll
  for (int ni = 0; ni < 4; ++ni) {
#pragma unroll
    for (int j = 0; j < 4; ++j) {
      size_t row = (size_t)b * 1024 + qrow0 + lg * 4 + j;
      int col = h * 64 + ni * 16 + l16;
      O16[row * 1024 + col] = f2b(o[ni][j] / lsum[j]);
    }
  }
}

extern "C" void kernel_launch(void* const* d_in, const int* in_sizes, int n_in,
                              void* d_out, int out_size, void* d_ws, size_t ws_size,
                              hipStream_t stream) {
  const float* x = (const float*)d_in[0];
  const float* ctx = (const float*)d_in[1];
  const float* dsim = (const float*)d_in[2];
  const int* mask = (const int*)d_in[3];
  const int* cmask = (const int*)d_in[4];
  const float* Wq = (const float*)d_in[5];
  const float* Wkv = (const float*)d_in[6];
  const float* Wout = (const float*)d_in[7];
  const float* bout = (const float*)d_in[8];
  const float* beta = (const float*)d_in[9];

  char* ws = (char*)d_ws;
  u16t* q16 = (u16t*)(ws + (0ull << 20));     //  4 MiB (2048x1024)
  u16t* kv16 = (u16t*)(ws + (4ull << 20));    // 32 MiB (8192x2048)
  u16t* vT16 = (u16t*)(ws + (36ull << 20));   // 16 MiB (2,16,64,4096)
  u16t* O16 = (u16t*)(ws + (52ull << 20));    //  4 MiB (2048x1024)
  u16t* x16 = (u16t*)(ws + (56ull << 20));    //  4 MiB
  u16t* ctx16 = (u16t*)(ws + (60ull << 20));  // 16 MiB
  u16t* WqT = (u16t*)(ws + (76ull << 20));    //  2 MiB
  u16t* WkvT = (u16t*)(ws + (78ull << 20));   //  4 MiB
  u16t* WoutT = (u16t*)(ws + (82ull << 20));  //  2 MiB

  float* outp = (float*)d_out;
  float* pre = outp + (size_t)2 * 1024 * 1024;

  k_cvt<<<2048, 256, 0, stream>>>(x, x16, 524288);
  k_cvt<<<8192, 256, 0, stream>>>(ctx, ctx16, 2097152);
  k_transpose_w<<<dim3(16, 16), 256, 0, stream>>>(Wq, WqT, 1024, 1024);
  k_transpose_w<<<dim3(32, 16), 256, 0, stream>>>(Wkv, WkvT, 1024, 2048);
  k_transpose_w<<<dim3(16, 16), 256, 0, stream>>>(Wout, WoutT, 1024, 1024);

  // q = x @ Wq   (2048x1024) bf16
  k_gemm_bt<0, 0><<<128, 256, 0, stream>>>(x16, WqT, (void*)q16, nullptr, 1024, 1024, 1024, 1024, 8);
  // kv = ctx @ Wkv (8192x2048) bf16
  k_gemm_bt<0, 0><<<1024, 256, 0, stream>>>(ctx16, WkvT, (void*)kv16, nullptr, 1024, 1024, 1024, 2048, 16);
  // v -> per-head transposed
  k_transpose_v<<<dim3(64, 16, 2), 256, 0, stream>>>(kv16, vT16);
  // fused QK^T + pre-store + softmax + PV
  k_attn<<<512, 256, 0, stream>>>(q16, kv16, vT16, dsim, mask, cmask, beta, pre, O16);
  // out = O @ Wout + bout  (f32)
  k_gemm_bt<1, 1><<<128, 256, 0, stream>>>(O16, WoutT, d_out, bout, 1024, 1024, 1024, 1024, 8);
}

// Round 4
// 269.423 us; speedup vs baseline: 1.3463x; 1.1240x over previous
//
#include <hip/hip_runtime.h>
#include <cstdint>
#include <cstddef>

typedef unsigned short u16t;
typedef __attribute__((ext_vector_type(4))) float f32x4;
typedef __attribute__((ext_vector_type(8))) __bf16 bf16x8;
typedef __attribute__((ext_vector_type(4))) __bf16 bf16x4;
typedef __attribute__((ext_vector_type(8))) unsigned short u16x8;
typedef __attribute__((ext_vector_type(4))) unsigned short u16x4;

#define INFF __builtin_inff()

__device__ __forceinline__ u16t f2b(float f) {
  union { float f; unsigned u; } x; x.f = f;
  unsigned r = x.u + 0x7FFFu + ((x.u >> 16) & 1u);   // RNE
  return (u16t)(r >> 16);
}

// async global->LDS, 16B per lane. LDS dest = wave-uniform base + lane*16.
__device__ __forceinline__ void gload16(const u16t* g, u16t* l) {
  __builtin_amdgcn_global_load_lds((const __attribute__((address_space(1))) void*)g,
                                   (__attribute__((address_space(3))) void*)l, 16, 0, 0);
}

// ---------------- fp32 -> bf16 convert (vectorized) ----------------
__global__ __launch_bounds__(256) void k_cvt(const float* __restrict__ s,
                                             u16t* __restrict__ d, int n4) {
  int i = blockIdx.x * 256 + threadIdx.x;
  if (i >= n4) return;
  f32x4 v = *(const f32x4*)(s + (size_t)i * 4);
  u16x4 o;
  o[0] = f2b(v[0]); o[1] = f2b(v[1]); o[2] = f2b(v[2]); o[3] = f2b(v[3]);
  *(u16x4*)(d + (size_t)i * 4) = o;
}

// ---------------- fp32 (R x C) -> bf16 transposed (C x R) ----------------
__global__ __launch_bounds__(256) void k_transpose_w(const float* __restrict__ src,
                                                     u16t* __restrict__ dst,
                                                     int R, int C) {
  __shared__ float tile[64 * 65];
  const int t = threadIdx.x;
  const int cb = blockIdx.x * 64, rb = blockIdx.y * 64;
#pragma unroll
  for (int it = 0; it < 4; ++it) {
    int c = it * 256 + t;
    int r = c >> 4, ch = c & 15;
    f32x4 v = *(const f32x4*)(src + (size_t)(rb + r) * C + cb + ch * 4);
    float* dp = &tile[r * 65 + ch * 4];
    dp[0] = v[0]; dp[1] = v[1]; dp[2] = v[2]; dp[3] = v[3];
  }
  __syncthreads();
#pragma unroll
  for (int it = 0; it < 2; ++it) {
    int c = it * 256 + t;
    int dr = c >> 3, ch = c & 7;
    u16x8 o;
#pragma unroll
    for (int i = 0; i < 8; ++i) o[i] = f2b(tile[(ch * 8 + i) * 65 + dr]);
    *(u16x8*)(dst + (size_t)(cb + dr) * R + rb + ch * 8) = o;
  }
}

// ---------------- v half of kv -> per-head transposed vT ----------------
__global__ __launch_bounds__(256) void k_transpose_v(const u16t* __restrict__ kv16,
                                                     u16t* __restrict__ vT) {
  __shared__ u16t tile[64 * 65];
  const int t = threadIdx.x;
  const int kvb = blockIdx.x * 64;
  const int h = blockIdx.y, b = blockIdx.z;
#pragma unroll
  for (int it = 0; it < 2; ++it) {
    int c = it * 256 + t;
    int r = c >> 3, ch = c & 7;
    u16x8 v = *(const u16x8*)(kv16 + (size_t)(b * 4096 + kvb + r) * 2048 + 1024 + h * 64 + ch * 8);
    u16t* dp = &tile[r * 65 + ch * 8];
#pragma unroll
    for (int i = 0; i < 8; ++i) dp[i] = v[i];
  }
  __syncthreads();
#pragma unroll
  for (int it = 0; it < 2; ++it) {
    int c = it * 256 + t;
    int dr = c >> 3, ch = c & 7;
    u16x8 o;
#pragma unroll
    for (int i = 0; i < 8; ++i) o[i] = tile[(ch * 8 + i) * 65 + dr];
    *(u16x8*)(vT + ((size_t)(b * 16 + h) * 64 + dr) * 4096 + kvb + ch * 8) = o;
  }
}

// ---------------- bf16 GEMM: C(MxN) = A(MxK) @ Bt(NxK)^T ----------------
// 128x128 tile, BK=64, 4 waves, global_load_lds staging (m97 structure),
// XOR swizzle applied on the per-lane GLOBAL source address (LDS dest linear).
template <int OUTF32, int BIAS>
__global__ __launch_bounds__(256) void k_gemm_bt(const u16t* __restrict__ A,
                                                 const u16t* __restrict__ Bt,
                                                 void* __restrict__ C,
                                                 const float* __restrict__ bias,
                                                 int K, int lda, int ldb, int ldc, int nbx) {
  __shared__ u16t As[128 * 64];
  __shared__ u16t Bs[128 * 64];
  const int tid = threadIdx.x;
  const int lane = tid & 63, wid = tid >> 6;
  const int l16 = lane & 15, lg = lane >> 4;
  const int wr = wid >> 1, wc = wid & 1;
  // XCD-aware bijective swizzle (gridDim.x divisible by 8)
  const int g = blockIdx.x, per = gridDim.x >> 3;
  const int w = (g & 7) * per + (g >> 3);
  const int bx = w % nbx, by = w / nbx;
  const int brow = by * 128, bcol = bx * 128;
  const int sr = lane >> 3, chs = lane & 7;
  f32x4 acc[4][4] = {};

  for (int k0 = 0; k0 < K; k0 += 64) {
#pragma unroll
    for (int it = 0; it < 4; ++it) {
      int row = it * 32 + wid * 8 + sr;
      int ch = chs ^ (row & 7);
      gload16(A + (size_t)(brow + row) * lda + k0 + ch * 8, &As[it * 2048 + wid * 512]);
      gload16(Bt + (size_t)(bcol + row) * ldb + k0 + ch * 8, &Bs[it * 2048 + wid * 512]);
    }
    __syncthreads();
#pragma unroll
    for (int kk = 0; kk < 2; ++kk) {
      bf16x8 af[4], bfv[4];
#pragma unroll
      for (int mi = 0; mi < 4; ++mi) {
        int row = wr * 64 + mi * 16 + l16;
        int kch = (kk * 4 + lg) ^ (row & 7);
        af[mi] = *(const bf16x8*)(&As[row * 64 + kch * 8]);
      }
#pragma unroll
      for (int ni = 0; ni < 4; ++ni) {
        int row = wc * 64 + ni * 16 + l16;
        int kch = (kk * 4 + lg) ^ (row & 7);
        bfv[ni] = *(const bf16x8*)(&Bs[row * 64 + kch * 8]);
      }
#pragma unroll
      for (int mi = 0; mi < 4; ++mi)
#pragma unroll
        for (int ni = 0; ni < 4; ++ni)
          acc[mi][ni] = __builtin_amdgcn_mfma_f32_16x16x32_bf16(af[mi], bfv[ni], acc[mi][ni], 0, 0, 0);
    }
    __syncthreads();
  }
#pragma unroll
  for (int mi = 0; mi < 4; ++mi) {
#pragma unroll
    for (int ni = 0; ni < 4; ++ni) {
#pragma unroll
      for (int j = 0; j < 4; ++j) {
        size_t row = (size_t)brow + wr * 64 + mi * 16 + lg * 4 + j;
        int col = bcol + wc * 64 + ni * 16 + l16;
        float v = acc[mi][ni][j];
        if (BIAS) v += bias[col];
        if (OUTF32)
          __builtin_nontemporal_store(v, (float*)C + row * ldc + col);
        else
          ((u16t*)C)[row * ldc + col] = f2b(v);
      }
    }
  }
}

// ---------------- fused attention (swapped-QK^T: S^T = K @ Q^T) ----------------
// Lane holds S[q=l16][kv=kb*16+lg*4+j]: vectorized pre-stores (f32x4),
// 8B P LDS writes, scalar per-lane softmax state.
__global__ __launch_bounds__(256) void k_attn(const u16t* __restrict__ q16,
                                              const u16t* __restrict__ kv16,
                                              const u16t* __restrict__ vT16,
                                              const float* __restrict__ dsim,
                                              const int* __restrict__ mask,
                                              const int* __restrict__ cmask,
                                              const float* __restrict__ beta_p,
                                              float* __restrict__ pre,
                                              u16t* __restrict__ O16) {
  __shared__ u16t Ks[2][128 * 64];   // [kv 128][hd 64] swizzled
  __shared__ u16t Vs[2][64 * 128];   // [hd 64][kv 128] swizzled
  __shared__ u16t Ps[4 * 16 * 128];  // per-wave P tile [q 16][kv 128] swizzled

  const int tid = threadIdx.x;
  const int lane = tid & 63, wid = tid >> 6;
  const int l16 = lane & 15, lg = lane >> 4;
  // XCD swizzle: w = (g%8)*64 + g/8 ; nb fastest so same (b,h) groups stay on one XCD
  const int g = blockIdx.x;
  const int w = (g & 7) * 64 + (g >> 3);
  const int nb = w & 15, hb = w >> 4;
  const int h = hb & 15, b = hb >> 4;
  const float beta = beta_p[0];
  const int qrow0 = nb * 64 + wid * 16;

  bf16x8 aq0, aq1;
  {
    const u16t* qp = q16 + (size_t)(b * 1024 + qrow0 + l16) * 1024 + h * 64 + lg * 8;
    aq0 = *(const bf16x8*)(qp);
    aq1 = *(const bf16x8*)(qp + 32);
  }
  const bool qm = mask[b * 1024 + qrow0 + l16] != 0;

  const float ds0 = dsim[b * 4 + 0] * beta, ds1 = dsim[b * 4 + 1] * beta;
  const float ds2 = dsim[b * 4 + 2] * beta, ds3 = dsim[b * 4 + 3] * beta;

  float mrow = -INFF, lsum = 0.f;
  f32x4 o[4] = {};

  const u16t* kbase = kv16 + (size_t)b * 4096 * 2048 + (size_t)h * 64;
  const u16t* vbase = vT16 + (size_t)(b * 16 + h) * 64 * 4096;
  float* prerow = pre + (size_t)((b * 16 + h) * 1024 + qrow0 + l16) * 4096;  // this lane's q row
  const int* cmb = cmask + b * 4096;
  u16t* Pw = &Ps[wid * 2048];
  char* Pwb = (char*)Pw + l16 * 256;      // this lane's P row base (bytes)
  const int pswz = (l16 & 7) << 4;        // row-XOR swizzle

  auto stage = [&](int bufi, int kv0s) {
    u16t* Kb = &Ks[bufi][wid * 2048];
    u16t* Vb = &Vs[bufi][wid * 2048];
#pragma unroll
    for (int it = 0; it < 4; ++it) {
      int row = wid * 32 + it * 8 + (lane >> 3);
      int ch = (lane & 7) ^ (row & 7);
      gload16(kbase + (size_t)(kv0s + row) * 2048 + ch * 8, Kb + it * 512);
    }
#pragma unroll
    for (int it = 0; it < 4; ++it) {
      int row = wid * 16 + it * 4 + (lane >> 4);
      int ch = (lane & 15) ^ (row & 7);
      gload16(vbase + (size_t)row * 4096 + kv0s + ch * 8, Vb + it * 512);
    }
  };

  int cur = 0;
  stage(0, 0);
  __syncthreads();

  for (int t = 0; t < 32; ++t) {
    if (t + 1 < 32) stage(cur ^ 1, (t + 1) * 128);  // prefetch overlaps compute
    const u16t* Kc = &Ks[cur][0];
    const u16t* Vc = &Vs[cur][0];
    const int kv0 = t * 128;

    // S^T = K @ Q^T : lane gets S[q=l16][kv=kb*16+lg*4+j]
    f32x4 s[8];
#pragma unroll
    for (int kb = 0; kb < 8; ++kb) {
      f32x4 acc = {0.f, 0.f, 0.f, 0.f};
      int row = kb * 16 + l16;
      bf16x8 bk0 = *(const bf16x8*)(&Kc[row * 64 + ((lg ^ (row & 7)) << 3)]);
      bf16x8 bk1 = *(const bf16x8*)(&Kc[row * 64 + (((4 + lg) ^ (row & 7)) << 3)]);
      acc = __builtin_amdgcn_mfma_f32_16x16x32_bf16(bk0, aq0, acc, 0, 0, 0);
      acc = __builtin_amdgcn_mfma_f32_16x16x32_bf16(bk1, aq1, acc, 0, 0, 0);
      s[kb] = acc;
    }

    // scale, vectorized pre-store, ds bias + faithful mask, row-max
    float tmax = -INFF;
#pragma unroll
    for (int kb = 0; kb < 8; ++kb) {
      const int colb = kv0 + kb * 16 + lg * 4;   // 4 | 1024 => same doc for j=0..3
      const float ds = (colb < 2048) ? (colb < 1024 ? ds0 : ds1) : (colb < 3072 ? ds2 : ds3);
      f32x4 sv4;
#pragma unroll
      for (int j = 0; j < 4; ++j) {
        float sv = s[kb][j] * 0.03125f;  // * d^-0.5
        sv4[j] = sv;
        bool km = cmb[colb + j] != 0;
        float t2 = sv + ds;
        if (!(qm && km)) t2 = 0.f;
        if (t2 == 0.f) t2 = -INFF;
        s[kb][j] = t2;
        tmax = fmaxf(tmax, t2);
      }
      __builtin_nontemporal_store(sv4, (f32x4*)(prerow + colb));
    }
    tmax = fmaxf(tmax, __shfl_xor(tmax, 16, 64));
    tmax = fmaxf(tmax, __shfl_xor(tmax, 32, 64));
    const float mn = fmaxf(mrow, tmax);
    const float fs = (mn == -INFF) ? 0.f : __expf(mrow - mn);
    mrow = mn;

    // P = exp(t - m) -> 8B LDS writes in A-frag layout [q=l16][kv]
    float psum = 0.f;
#pragma unroll
    for (int kb = 0; kb < 8; ++kb) {
      bf16x4 pb;
#pragma unroll
      for (int j = 0; j < 4; ++j) {
        float p = (mrow == -INFF) ? 0.f : __expf(s[kb][j] - mrow);
        psum += p;
        pb[j] = (__bf16)p;
      }
      *(bf16x4*)(Pwb + ((kb * 32 + lg * 8) ^ pswz)) = pb;
    }
    asm volatile("" ::: "memory");
    psum += __shfl_xor(psum, 16, 64);
    psum += __shfl_xor(psum, 32, 64);
    lsum = lsum * fs + psum;

    // broadcast rescale factors to O-row owners (O row q = lg*4+j)
    float fsj[4];
#pragma unroll
    for (int j = 0; j < 4; ++j) fsj[j] = __shfl(fs, lg * 4 + j, 64);
#pragma unroll
    for (int ni = 0; ni < 4; ++ni)
#pragma unroll
      for (int j = 0; j < 4; ++j) o[ni][j] *= fsj[j];

    // O += P @ V
#pragma unroll
    for (int kk2 = 0; kk2 < 4; ++kk2) {
      bf16x8 pa = *(const bf16x8*)(Pwb + ((kk2 * 64 + lg * 16) ^ pswz));
#pragma unroll
      for (int ni = 0; ni < 4; ++ni) {
        int vrow = ni * 16 + l16;
        bf16x8 vb = *(const bf16x8*)(&Vc[vrow * 128 + (((kk2 * 4 + lg) ^ (vrow & 7)) << 3)]);
        o[ni] = __builtin_amdgcn_mfma_f32_16x16x32_bf16(pa, vb, o[ni], 0, 0, 0);
      }
    }
    __syncthreads();  // drains prefetch vmcnt + protects buffer swap
    cur ^= 1;
  }

  float lsj[4];
#pragma unroll
  for (int j = 0; j < 4; ++j) lsj[j] = __shfl(lsum, lg * 4 + j, 64);
#pragma unroll
  for (int ni = 0; ni < 4; ++ni) {
#pragma unroll
    for (int j = 0; j < 4; ++j) {
      size_t row = (size_t)b * 1024 + qrow0 + lg * 4 + j;
      int col = h * 64 + ni * 16 + l16;
      O16[row * 1024 + col] = f2b(o[ni][j] / lsj[j]);
    }
  }
}

extern "C" void kernel_launch(void* const* d_in, const int* in_sizes, int n_in,
                              void* d_out, int out_size, void* d_ws, size_t ws_size,
                              hipStream_t stream) {
  const float* x = (const float*)d_in[0];
  const float* ctx = (const float*)d_in[1];
  const float* dsim = (const float*)d_in[2];
  const int* mask = (const int*)d_in[3];
  const int* cmask = (const int*)d_in[4];
  const float* Wq = (const float*)d_in[5];
  const float* Wkv = (const float*)d_in[6];
  const float* Wout = (const float*)d_in[7];
  const float* bout = (const float*)d_in[8];
  const float* beta = (const float*)d_in[9];

  char* ws = (char*)d_ws;
  u16t* q16 = (u16t*)(ws + (0ull << 20));     //  4 MiB (2048x1024)
  u16t* kv16 = (u16t*)(ws + (4ull << 20));    // 32 MiB (8192x2048)
  u16t* vT16 = (u16t*)(ws + (36ull << 20));   // 16 MiB (2,16,64,4096)
  u16t* O16 = (u16t*)(ws + (52ull << 20));    //  4 MiB (2048x1024)
  u16t* x16 = (u16t*)(ws + (56ull << 20));    //  4 MiB
  u16t* ctx16 = (u16t*)(ws + (60ull << 20));  // 16 MiB
  u16t* WqT = (u16t*)(ws + (76ull << 20));    //  2 MiB
  u16t* WkvT = (u16t*)(ws + (78ull << 20));   //  4 MiB
  u16t* WoutT = (u16t*)(ws + (82ull << 20));  //  2 MiB

  float* outp = (float*)d_out;
  float* pre = outp + (size_t)2 * 1024 * 1024;

  k_cvt<<<2048, 256, 0, stream>>>(x, x16, 524288);
  k_cvt<<<8192, 256, 0, stream>>>(ctx, ctx16, 2097152);
  k_transpose_w<<<dim3(16, 16), 256, 0, stream>>>(Wq, WqT, 1024, 1024);
  k_transpose_w<<<dim3(32, 16), 256, 0, stream>>>(Wkv, WkvT, 1024, 2048);
  k_transpose_w<<<dim3(16, 16), 256, 0, stream>>>(Wout, WoutT, 1024, 1024);

  // q = x @ Wq   (2048x1024) bf16
  k_gemm_bt<0, 0><<<128, 256, 0, stream>>>(x16, WqT, (void*)q16, nullptr, 1024, 1024, 1024, 1024, 8);
  // kv = ctx @ Wkv (8192x2048) bf16
  k_gemm_bt<0, 0><<<1024, 256, 0, stream>>>(ctx16, WkvT, (void*)kv16, nullptr, 1024, 1024, 1024, 2048, 16);
  // v -> per-head transposed
  k_transpose_v<<<dim3(64, 16, 2), 256, 0, stream>>>(kv16, vT16);
  // fused QK^T + pre-store + softmax + PV
  k_attn<<<512, 256, 0, stream>>>(q16, kv16, vT16, dsim, mask, cmask, beta, pre, O16);
  // out = O @ Wout + bout  (f32)
  k_gemm_bt<1, 1><<<128, 256, 0, stream>>>(O16, WoutT, d_out, bout, 1024, 1024, 1024, 1024, 8);
}

// Round 5
// 263.403 us; speedup vs baseline: 1.3771x; 1.0229x over previous
//
#include <hip/hip_runtime.h>
#include <cstdint>
#include <cstddef>

typedef unsigned short u16t;
typedef __attribute__((ext_vector_type(4))) float f32x4;
typedef __attribute__((ext_vector_type(4))) int i32x4;
typedef __attribute__((ext_vector_type(8))) __bf16 bf16x8;
typedef __attribute__((ext_vector_type(4))) __bf16 bf16x4;
typedef __attribute__((ext_vector_type(8))) unsigned short u16x8;
typedef __attribute__((ext_vector_type(4))) unsigned short u16x4;

#define INFF __builtin_inff()

__device__ __forceinline__ u16t f2b(float f) {
  union { float f; unsigned u; } x; x.f = f;
  unsigned r = x.u + 0x7FFFu + ((x.u >> 16) & 1u);   // RNE
  return (u16t)(r >> 16);
}

// async global->LDS, 16B per lane. LDS dest = wave-uniform base + lane*16.
__device__ __forceinline__ void gload16(const u16t* g, u16t* l) {
  __builtin_amdgcn_global_load_lds((const __attribute__((address_space(1))) void*)g,
                                   (__attribute__((address_space(3))) void*)l, 16, 0, 0);
}

// ---------------- fused prep: cvt x, cvt ctx, bias table ----------------
// blocks [0,2048): x cvt; [2048,10240): ctx cvt; [10240,10248): bias.
// biasf[b][c] = cmask[b][c] ? dsim[b][c/1024]*beta : -inf
__global__ __launch_bounds__(256) void k_prep(const float* __restrict__ x,
                                              const float* __restrict__ ctx,
                                              u16t* __restrict__ x16,
                                              u16t* __restrict__ ctx16,
                                              const int* __restrict__ cmask,
                                              const float* __restrict__ dsim,
                                              const float* __restrict__ beta_p,
                                              float* __restrict__ biasf) {
  const int bx = blockIdx.x, tid = threadIdx.x;
  if (bx < 2048) {
    int i = bx * 256 + tid;
    f32x4 v = *(const f32x4*)(x + (size_t)i * 4);
    u16x4 o;
    o[0] = f2b(v[0]); o[1] = f2b(v[1]); o[2] = f2b(v[2]); o[3] = f2b(v[3]);
    *(u16x4*)(x16 + (size_t)i * 4) = o;
  } else if (bx < 10240) {
    int i = (bx - 2048) * 256 + tid;
    f32x4 v = *(const f32x4*)(ctx + (size_t)i * 4);
    u16x4 o;
    o[0] = f2b(v[0]); o[1] = f2b(v[1]); o[2] = f2b(v[2]); o[3] = f2b(v[3]);
    *(u16x4*)(ctx16 + (size_t)i * 4) = o;
  } else {
    int idx = (bx - 10240) * 256 + tid;   // [0,2048)
    int c = idx * 4;                       // 4 consecutive cols, same doc
    const float beta = beta_p[0];
    const float ds = dsim[(c >> 12) * 4 + ((c & 4095) >> 10)] * beta;
    i32x4 cm = *(const i32x4*)(cmask + c);
    f32x4 bv;
#pragma unroll
    for (int j = 0; j < 4; ++j) bv[j] = cm[j] ? ds : -INFF;
    *(f32x4*)(biasf + c) = bv;
  }
}

// ---------------- fused 3x weight transpose: fp32 (1024 x C) -> bf16 (C x 1024) ----------------
// blockIdx.x: [0,16) Wq, [16,48) Wkv, [48,64) Wout
__global__ __launch_bounds__(256) void k_transpose_w3(const float* __restrict__ Wq,
                                                      const float* __restrict__ Wkv,
                                                      const float* __restrict__ Wout,
                                                      u16t* __restrict__ WqT,
                                                      u16t* __restrict__ WkvT,
                                                      u16t* __restrict__ WoutT) {
  __shared__ float tile[64 * 65];
  const int t = threadIdx.x;
  const int bxx = blockIdx.x;
  const float* src; u16t* dst; int C, cb;
  if (bxx < 16)      { src = Wq;   dst = WqT;   C = 1024; cb = bxx * 64; }
  else if (bxx < 48) { src = Wkv;  dst = WkvT;  C = 2048; cb = (bxx - 16) * 64; }
  else               { src = Wout; dst = WoutT; C = 1024; cb = (bxx - 48) * 64; }
  const int rb = blockIdx.y * 64;
#pragma unroll
  for (int it = 0; it < 4; ++it) {
    int c = it * 256 + t;
    int r = c >> 4, ch = c & 15;
    f32x4 v = *(const f32x4*)(src + (size_t)(rb + r) * C + cb + ch * 4);
    float* dp = &tile[r * 65 + ch * 4];
    dp[0] = v[0]; dp[1] = v[1]; dp[2] = v[2]; dp[3] = v[3];
  }
  __syncthreads();
#pragma unroll
  for (int it = 0; it < 2; ++it) {
    int c = it * 256 + t;
    int dr = c >> 3, ch = c & 7;
    u16x8 o;
#pragma unroll
    for (int i = 0; i < 8; ++i) o[i] = f2b(tile[(ch * 8 + i) * 65 + dr]);
    *(u16x8*)(dst + (size_t)(cb + dr) * 1024 + rb + ch * 8) = o;
  }
}

// ---------------- v half of kv -> per-head transposed vT ----------------
__global__ __launch_bounds__(256) void k_transpose_v(const u16t* __restrict__ kv16,
                                                     u16t* __restrict__ vT) {
  __shared__ u16t tile[64 * 65];
  const int t = threadIdx.x;
  const int kvb = blockIdx.x * 64;
  const int h = blockIdx.y, b = blockIdx.z;
#pragma unroll
  for (int it = 0; it < 2; ++it) {
    int c = it * 256 + t;
    int r = c >> 3, ch = c & 7;
    u16x8 v = *(const u16x8*)(kv16 + (size_t)(b * 4096 + kvb + r) * 2048 + 1024 + h * 64 + ch * 8);
    u16t* dp = &tile[r * 65 + ch * 8];
#pragma unroll
    for (int i = 0; i < 8; ++i) dp[i] = v[i];
  }
  __syncthreads();
#pragma unroll
  for (int it = 0; it < 2; ++it) {
    int c = it * 256 + t;
    int dr = c >> 3, ch = c & 7;
    u16x8 o;
#pragma unroll
    for (int i = 0; i < 8; ++i) o[i] = tile[(ch * 8 + i) * 65 + dr];
    *(u16x8*)(vT + ((size_t)(b * 16 + h) * 64 + dr) * 4096 + kvb + ch * 8) = o;
  }
}

// ---------------- bf16 GEMM: C(MxN) = oscale * A(MxK) @ Bt(NxK)^T ----------------
// 128x128 tile, BK=64, 4 waves, global_load_lds staging (m97 structure),
// XOR swizzle applied on the per-lane GLOBAL source address (LDS dest linear).
template <int OUTF32, int BIAS>
__global__ __launch_bounds__(256) void k_gemm_bt(const u16t* __restrict__ A,
                                                 const u16t* __restrict__ Bt,
                                                 void* __restrict__ C,
                                                 const float* __restrict__ bias,
                                                 float oscale,
                                                 int K, int lda, int ldb, int ldc, int nbx) {
  __shared__ u16t As[128 * 64];
  __shared__ u16t Bs[128 * 64];
  const int tid = threadIdx.x;
  const int lane = tid & 63, wid = tid >> 6;
  const int l16 = lane & 15, lg = lane >> 4;
  const int wr = wid >> 1, wc = wid & 1;
  // XCD-aware bijective swizzle (gridDim.x divisible by 8)
  const int g = blockIdx.x, per = gridDim.x >> 3;
  const int w = (g & 7) * per + (g >> 3);
  const int bx = w % nbx, by = w / nbx;
  const int brow = by * 128, bcol = bx * 128;
  const int sr = lane >> 3, chs = lane & 7;
  f32x4 acc[4][4] = {};

  for (int k0 = 0; k0 < K; k0 += 64) {
#pragma unroll
    for (int it = 0; it < 4; ++it) {
      int row = it * 32 + wid * 8 + sr;
      int ch = chs ^ (row & 7);
      gload16(A + (size_t)(brow + row) * lda + k0 + ch * 8, &As[it * 2048 + wid * 512]);
      gload16(Bt + (size_t)(bcol + row) * ldb + k0 + ch * 8, &Bs[it * 2048 + wid * 512]);
    }
    __syncthreads();
#pragma unroll
    for (int kk = 0; kk < 2; ++kk) {
      bf16x8 af[4], bfv[4];
#pragma unroll
      for (int mi = 0; mi < 4; ++mi) {
        int row = wr * 64 + mi * 16 + l16;
        int kch = (kk * 4 + lg) ^ (row & 7);
        af[mi] = *(const bf16x8*)(&As[row * 64 + kch * 8]);
      }
#pragma unroll
      for (int ni = 0; ni < 4; ++ni) {
        int row = wc * 64 + ni * 16 + l16;
        int kch = (kk * 4 + lg) ^ (row & 7);
        bfv[ni] = *(const bf16x8*)(&Bs[row * 64 + kch * 8]);
      }
#pragma unroll
      for (int mi = 0; mi < 4; ++mi)
#pragma unroll
        for (int ni = 0; ni < 4; ++ni)
          acc[mi][ni] = __builtin_amdgcn_mfma_f32_16x16x32_bf16(af[mi], bfv[ni], acc[mi][ni], 0, 0, 0);
    }
    __syncthreads();
  }
#pragma unroll
  for (int mi = 0; mi < 4; ++mi) {
#pragma unroll
    for (int ni = 0; ni < 4; ++ni) {
#pragma unroll
      for (int j = 0; j < 4; ++j) {
        size_t row = (size_t)brow + wr * 64 + mi * 16 + lg * 4 + j;
        int col = bcol + wc * 64 + ni * 16 + l16;
        float v = acc[mi][ni][j] * oscale;
        if (BIAS) v += bias[col];
        if (OUTF32)
          __builtin_nontemporal_store(v, (float*)C + row * ldc + col);
        else
          ((u16t*)C)[row * ldc + col] = f2b(v);
      }
    }
  }
}

// ---------------- fused attention (swapped-QK^T: S^T = K @ Q^T) ----------------
// q16 is pre-scaled by d^-0.5 (exact 2^-5). Lane holds S[q=l16][kv=kb*16+lg*4+j].
// Per-column bias (ds or -inf) precomputed; skip-rescale when max unchanged.
__global__ __launch_bounds__(256) void k_attn(const u16t* __restrict__ q16,
                                              const u16t* __restrict__ kv16,
                                              const u16t* __restrict__ vT16,
                                              const float* __restrict__ biasf,
                                              const int* __restrict__ mask,
                                              float* __restrict__ pre,
                                              u16t* __restrict__ O16) {
  __shared__ u16t Ks[2][128 * 64];   // [kv 128][hd 64] swizzled
  __shared__ u16t Vs[2][64 * 128];   // [hd 64][kv 128] swizzled
  __shared__ u16t Ps[4 * 16 * 128];  // per-wave P tile [q 16][kv 128] swizzled

  const int tid = threadIdx.x;
  const int lane = tid & 63, wid = tid >> 6;
  const int l16 = lane & 15, lg = lane >> 4;
  // XCD swizzle: w = (g%8)*64 + g/8 ; nb fastest so same (b,h) groups stay on one XCD
  const int g = blockIdx.x;
  const int w = (g & 7) * 64 + (g >> 3);
  const int nb = w & 15, hb = w >> 4;
  const int h = hb & 15, b = hb >> 4;
  const int qrow0 = nb * 64 + wid * 16;

  bf16x8 aq0, aq1;
  {
    const u16t* qp = q16 + (size_t)(b * 1024 + qrow0 + l16) * 1024 + h * 64 + lg * 8;
    aq0 = *(const bf16x8*)(qp);
    aq1 = *(const bf16x8*)(qp + 32);
  }
  const bool qm = mask[b * 1024 + qrow0 + l16] != 0;

  float mrow = -INFF, lsum = 0.f;
  f32x4 o[4] = {};

  const u16t* kbase = kv16 + (size_t)b * 4096 * 2048 + (size_t)h * 64;
  const u16t* vbase = vT16 + (size_t)(b * 16 + h) * 64 * 4096;
  float* prerow = pre + (size_t)((b * 16 + h) * 1024 + qrow0 + l16) * 4096;  // this lane's q row
  const float* biasb = biasf + b * 4096;
  u16t* Pw = &Ps[wid * 2048];
  char* Pwb = (char*)Pw + l16 * 256;      // this lane's P row base (bytes)
  const int pswz = (l16 & 7) << 4;        // row-XOR swizzle

  auto stage = [&](int bufi, int kv0s) {
    u16t* Kb = &Ks[bufi][wid * 2048];
    u16t* Vb = &Vs[bufi][wid * 2048];
#pragma unroll
    for (int it = 0; it < 4; ++it) {
      int row = wid * 32 + it * 8 + (lane >> 3);
      int ch = (lane & 7) ^ (row & 7);
      gload16(kbase + (size_t)(kv0s + row) * 2048 + ch * 8, Kb + it * 512);
    }
#pragma unroll
    for (int it = 0; it < 4; ++it) {
      int row = wid * 16 + it * 4 + (lane >> 4);
      int ch = (lane & 15) ^ (row & 7);
      gload16(vbase + (size_t)row * 4096 + kv0s + ch * 8, Vb + it * 512);
    }
  };

  int cur = 0;
  stage(0, 0);
  __syncthreads();

  for (int t = 0; t < 32; ++t) {
    if (t + 1 < 32) stage(cur ^ 1, (t + 1) * 128);  // prefetch overlaps compute
    const u16t* Kc = &Ks[cur][0];
    const u16t* Vc = &Vs[cur][0];
    const int kv0 = t * 128;

    // S^T = K @ Q^T : lane gets S[q=l16][kv=kb*16+lg*4+j] (already d^-0.5 scaled)
    f32x4 s[8];
#pragma unroll
    for (int kb = 0; kb < 8; ++kb) {
      f32x4 acc = {0.f, 0.f, 0.f, 0.f};
      int row = kb * 16 + l16;
      bf16x8 bk0 = *(const bf16x8*)(&Kc[row * 64 + ((lg ^ (row & 7)) << 3)]);
      bf16x8 bk1 = *(const bf16x8*)(&Kc[row * 64 + (((4 + lg) ^ (row & 7)) << 3)]);
      acc = __builtin_amdgcn_mfma_f32_16x16x32_bf16(bk0, aq0, acc, 0, 0, 0);
      acc = __builtin_amdgcn_mfma_f32_16x16x32_bf16(bk1, aq1, acc, 0, 0, 0);
      s[kb] = acc;
    }

    // vectorized pre-store, bias add (+faithful mask), row-max
    float tmax = -INFF;
#pragma unroll
    for (int kb = 0; kb < 8; ++kb) {
      const int colb = kv0 + kb * 16 + lg * 4;   // 4 | 1024 => same doc for j=0..3
      __builtin_nontemporal_store(s[kb], (f32x4*)(prerow + colb));
      f32x4 bv = *(const f32x4*)(biasb + colb);
#pragma unroll
      for (int j = 0; j < 4; ++j) {
        float t2 = s[kb][j] + bv[j];   // masked col: bv=-inf -> t2=-inf
        if (!qm) t2 = 0.f;
        if (t2 == 0.f) t2 = -INFF;     // faithful zero->-inf
        s[kb][j] = t2;
        tmax = fmaxf(tmax, t2);
      }
    }
    tmax = fmaxf(tmax, __shfl_xor(tmax, 16, 64));
    tmax = fmaxf(tmax, __shfl_xor(tmax, 32, 64));
    const float mold = mrow;
    const float mn = fmaxf(mold, tmax);
    const bool nochange = __all(mn == mold);
    mrow = mn;

    // P = exp(t - m) -> 8B LDS writes in A-frag layout [q=l16][kv]
    float psum = 0.f;
#pragma unroll
    for (int kb = 0; kb < 8; ++kb) {
      bf16x4 pb;
#pragma unroll
      for (int j = 0; j < 4; ++j) {
        float p = (mn == -INFF) ? 0.f : __expf(s[kb][j] - mn);
        psum += p;
        pb[j] = (__bf16)p;
      }
      *(bf16x4*)(Pwb + ((kb * 32 + lg * 8) ^ pswz)) = pb;
    }
    asm volatile("" ::: "memory");
    psum += __shfl_xor(psum, 16, 64);
    psum += __shfl_xor(psum, 32, 64);

    if (nochange) {
      lsum += psum;                      // fs == 1 for every lane: skip rescale
    } else {
      const float fs = (mn == -INFF) ? 0.f : __expf(mold - mn);
      lsum = lsum * fs + psum;
      float fsj[4];
#pragma unroll
      for (int j = 0; j < 4; ++j) fsj[j] = __shfl(fs, lg * 4 + j, 64);
#pragma unroll
      for (int ni = 0; ni < 4; ++ni)
#pragma unroll
        for (int j = 0; j < 4; ++j) o[ni][j] *= fsj[j];
    }

    // O += P @ V
#pragma unroll
    for (int kk2 = 0; kk2 < 4; ++kk2) {
      bf16x8 pa = *(const bf16x8*)(Pwb + ((kk2 * 64 + lg * 16) ^ pswz));
#pragma unroll
      for (int ni = 0; ni < 4; ++ni) {
        int vrow = ni * 16 + l16;
        bf16x8 vb = *(const bf16x8*)(&Vc[vrow * 128 + (((kk2 * 4 + lg) ^ (vrow & 7)) << 3)]);
        o[ni] = __builtin_amdgcn_mfma_f32_16x16x32_bf16(pa, vb, o[ni], 0, 0, 0);
      }
    }
    __syncthreads();  // drains prefetch vmcnt + protects buffer swap
    cur ^= 1;
  }

  float lsj[4];
#pragma unroll
  for (int j = 0; j < 4; ++j) lsj[j] = __shfl(lsum, lg * 4 + j, 64);
#pragma unroll
  for (int ni = 0; ni < 4; ++ni) {
#pragma unroll
    for (int j = 0; j < 4; ++j) {
      size_t row = (size_t)b * 1024 + qrow0 + lg * 4 + j;
      int col = h * 64 + ni * 16 + l16;
      O16[row * 1024 + col] = f2b(o[ni][j] / lsj[j]);
    }
  }
}

extern "C" void kernel_launch(void* const* d_in, const int* in_sizes, int n_in,
                              void* d_out, int out_size, void* d_ws, size_t ws_size,
                              hipStream_t stream) {
  const float* x = (const float*)d_in[0];
  const float* ctx = (const float*)d_in[1];
  const float* dsim = (const float*)d_in[2];
  const int* mask = (const int*)d_in[3];
  const int* cmask = (const int*)d_in[4];
  const float* Wq = (const float*)d_in[5];
  const float* Wkv = (const float*)d_in[6];
  const float* Wout = (const float*)d_in[7];
  const float* bout = (const float*)d_in[8];
  const float* beta = (const float*)d_in[9];

  char* ws = (char*)d_ws;
  u16t* q16 = (u16t*)(ws + (0ull << 20));     //  4 MiB (2048x1024), pre-scaled by d^-0.5
  u16t* kv16 = (u16t*)(ws + (4ull << 20));    // 32 MiB (8192x2048)
  u16t* vT16 = (u16t*)(ws + (36ull << 20));   // 16 MiB (2,16,64,4096)
  u16t* O16 = (u16t*)(ws + (52ull << 20));    //  4 MiB (2048x1024)
  u16t* x16 = (u16t*)(ws + (56ull << 20));    //  4 MiB
  u16t* ctx16 = (u16t*)(ws + (60ull << 20));  // 16 MiB
  u16t* WqT = (u16t*)(ws + (76ull << 20));    //  2 MiB
  u16t* WkvT = (u16t*)(ws + (78ull << 20));   //  4 MiB
  u16t* WoutT = (u16t*)(ws + (82ull << 20));  //  2 MiB
  float* biasf = (float*)(ws + (84ull << 20)); // 32 KiB (2 x 4096 f32)

  float* outp = (float*)d_out;
  float* pre = outp + (size_t)2 * 1024 * 1024;

  // fused cvt(x), cvt(ctx), bias table
  k_prep<<<10248, 256, 0, stream>>>(x, ctx, x16, ctx16, cmask, dsim, beta, biasf);
  // fused 3x weight transpose
  k_transpose_w3<<<dim3(64, 16), 256, 0, stream>>>(Wq, Wkv, Wout, WqT, WkvT, WoutT);

  // q = (x @ Wq) * d^-0.5   (2048x1024) bf16  (scale fold is exact: 2^-5)
  k_gemm_bt<0, 0><<<128, 256, 0, stream>>>(x16, WqT, (void*)q16, nullptr, 0.03125f, 1024, 1024, 1024, 1024, 8);
  // kv = ctx @ Wkv (8192x2048) bf16
  k_gemm_bt<0, 0><<<1024, 256, 0, stream>>>(ctx16, WkvT, (void*)kv16, nullptr, 1.0f, 1024, 1024, 1024, 2048, 16);
  // v -> per-head transposed
  k_transpose_v<<<dim3(64, 16, 2), 256, 0, stream>>>(kv16, vT16);
  // fused QK^T + pre-store + softmax + PV
  k_attn<<<512, 256, 0, stream>>>(q16, kv16, vT16, biasf, mask, pre, O16);
  // out = O @ Wout + bout  (f32)
  k_gemm_bt<1, 1><<<128, 256, 0, stream>>>(O16, WoutT, d_out, bout, 1.0f, 1024, 1024, 1024, 1024, 8);
}

// Round 6
// 261.893 us; speedup vs baseline: 1.3850x; 1.0058x over previous
//
#include <hip/hip_runtime.h>
#include <cstdint>
#include <cstddef>

typedef unsigned short u16t;
typedef __attribute__((ext_vector_type(4))) float f32x4;
typedef __attribute__((ext_vector_type(4))) int i32x4;
typedef __attribute__((ext_vector_type(8))) __bf16 bf16x8;
typedef __attribute__((ext_vector_type(4))) __bf16 bf16x4;
typedef __attribute__((ext_vector_type(8))) unsigned short u16x8;
typedef __attribute__((ext_vector_type(4))) unsigned short u16x4;

#define INFF __builtin_inff()

__device__ __forceinline__ u16t f2b(float f) {
  union { float f; unsigned u; } x; x.f = f;
  unsigned r = x.u + 0x7FFFu + ((x.u >> 16) & 1u);   // RNE
  return (u16t)(r >> 16);
}

// async global->LDS, 16B per lane. LDS dest = wave-uniform base + lane*16.
__device__ __forceinline__ void gload16(const u16t* g, u16t* l) {
  __builtin_amdgcn_global_load_lds((const __attribute__((address_space(1))) void*)g,
                                   (__attribute__((address_space(3))) void*)l, 16, 0, 0);
}

// ---------------- fused prep: cvt x, cvt ctx, bias table ----------------
// blocks [0,2048): x cvt; [2048,10240): ctx cvt; [10240,10248): bias.
// biasf[b][c] = cmask[b][c] ? dsim[b][c/1024]*beta : -inf
__global__ __launch_bounds__(256) void k_prep(const float* __restrict__ x,
                                              const float* __restrict__ ctx,
                                              u16t* __restrict__ x16,
                                              u16t* __restrict__ ctx16,
                                              const int* __restrict__ cmask,
                                              const float* __restrict__ dsim,
                                              const float* __restrict__ beta_p,
                                              float* __restrict__ biasf) {
  const int bx = blockIdx.x, tid = threadIdx.x;
  if (bx < 2048) {
    int i = bx * 256 + tid;
    f32x4 v = *(const f32x4*)(x + (size_t)i * 4);
    u16x4 o;
    o[0] = f2b(v[0]); o[1] = f2b(v[1]); o[2] = f2b(v[2]); o[3] = f2b(v[3]);
    *(u16x4*)(x16 + (size_t)i * 4) = o;
  } else if (bx < 10240) {
    int i = (bx - 2048) * 256 + tid;
    f32x4 v = *(const f32x4*)(ctx + (size_t)i * 4);
    u16x4 o;
    o[0] = f2b(v[0]); o[1] = f2b(v[1]); o[2] = f2b(v[2]); o[3] = f2b(v[3]);
    *(u16x4*)(ctx16 + (size_t)i * 4) = o;
  } else {
    int idx = (bx - 10240) * 256 + tid;   // [0,2048)
    int c = idx * 4;                       // 4 consecutive cols, same doc
    const float beta = beta_p[0];
    const float ds = dsim[(c >> 12) * 4 + ((c & 4095) >> 10)] * beta;
    i32x4 cm = *(const i32x4*)(cmask + c);
    f32x4 bv;
#pragma unroll
    for (int j = 0; j < 4; ++j) bv[j] = cm[j] ? ds : -INFF;
    *(f32x4*)(biasf + c) = bv;
  }
}

// ---------------- fused 3x weight transpose: fp32 (1024 x C) -> bf16 (C x 1024) ----------------
// blockIdx.x: [0,16) Wq, [16,48) Wkv, [48,64) Wout
__global__ __launch_bounds__(256) void k_transpose_w3(const float* __restrict__ Wq,
                                                      const float* __restrict__ Wkv,
                                                      const float* __restrict__ Wout,
                                                      u16t* __restrict__ WqT,
                                                      u16t* __restrict__ WkvT,
                                                      u16t* __restrict__ WoutT) {
  __shared__ float tile[64 * 65];
  const int t = threadIdx.x;
  const int bxx = blockIdx.x;
  const float* src; u16t* dst; int C, cb;
  if (bxx < 16)      { src = Wq;   dst = WqT;   C = 1024; cb = bxx * 64; }
  else if (bxx < 48) { src = Wkv;  dst = WkvT;  C = 2048; cb = (bxx - 16) * 64; }
  else               { src = Wout; dst = WoutT; C = 1024; cb = (bxx - 48) * 64; }
  const int rb = blockIdx.y * 64;
#pragma unroll
  for (int it = 0; it < 4; ++it) {
    int c = it * 256 + t;
    int r = c >> 4, ch = c & 15;
    f32x4 v = *(const f32x4*)(src + (size_t)(rb + r) * C + cb + ch * 4);
    float* dp = &tile[r * 65 + ch * 4];
    dp[0] = v[0]; dp[1] = v[1]; dp[2] = v[2]; dp[3] = v[3];
  }
  __syncthreads();
#pragma unroll
  for (int it = 0; it < 2; ++it) {
    int c = it * 256 + t;
    int dr = c >> 3, ch = c & 7;
    u16x8 o;
#pragma unroll
    for (int i = 0; i < 8; ++i) o[i] = f2b(tile[(ch * 8 + i) * 65 + dr]);
    *(u16x8*)(dst + (size_t)(cb + dr) * 1024 + rb + ch * 8) = o;
  }
}

// ---------------- bf16 GEMM: C(MxN) = oscale * A(MxK) @ Bt(NxK)^T ----------------
// 128x128 tile, BK=64, 4 waves, global_load_lds staging (m97 structure).
// MODE 0: bf16 C.  MODE 1: f32 C + bias.  MODE 2: kv-dual (k half -> C bf16
// compact ldc; v half -> C2 = vT (b,h,64,4096) transposed bf16).
template <int MODE>
__global__ __launch_bounds__(256) void k_gemm_bt(const u16t* __restrict__ A,
                                                 const u16t* __restrict__ Bt,
                                                 void* __restrict__ C,
                                                 u16t* __restrict__ C2,
                                                 const float* __restrict__ bias,
                                                 float oscale,
                                                 int K, int lda, int ldb, int ldc, int nbx) {
  __shared__ u16t As[128 * 64];
  __shared__ u16t Bs[128 * 64];
  const int tid = threadIdx.x;
  const int lane = tid & 63, wid = tid >> 6;
  const int l16 = lane & 15, lg = lane >> 4;
  const int wr = wid >> 1, wc = wid & 1;
  // XCD-aware bijective swizzle (gridDim.x divisible by 8)
  const int g = blockIdx.x, per = gridDim.x >> 3;
  const int w = (g & 7) * per + (g >> 3);
  const int bx = w % nbx, by = w / nbx;
  const int brow = by * 128, bcol = bx * 128;
  const int sr = lane >> 3, chs = lane & 7;
  f32x4 acc[4][4] = {};

  for (int k0 = 0; k0 < K; k0 += 64) {
#pragma unroll
    for (int it = 0; it < 4; ++it) {
      int row = it * 32 + wid * 8 + sr;
      int ch = chs ^ (row & 7);
      gload16(A + (size_t)(brow + row) * lda + k0 + ch * 8, &As[it * 2048 + wid * 512]);
      gload16(Bt + (size_t)(bcol + row) * ldb + k0 + ch * 8, &Bs[it * 2048 + wid * 512]);
    }
    __syncthreads();
#pragma unroll
    for (int kk = 0; kk < 2; ++kk) {
      bf16x8 af[4], bfv[4];
#pragma unroll
      for (int mi = 0; mi < 4; ++mi) {
        int row = wr * 64 + mi * 16 + l16;
        int kch = (kk * 4 + lg) ^ (row & 7);
        af[mi] = *(const bf16x8*)(&As[row * 64 + kch * 8]);
      }
#pragma unroll
      for (int ni = 0; ni < 4; ++ni) {
        int row = wc * 64 + ni * 16 + l16;
        int kch = (kk * 4 + lg) ^ (row & 7);
        bfv[ni] = *(const bf16x8*)(&Bs[row * 64 + kch * 8]);
      }
#pragma unroll
      for (int mi = 0; mi < 4; ++mi)
#pragma unroll
        for (int ni = 0; ni < 4; ++ni)
          acc[mi][ni] = __builtin_amdgcn_mfma_f32_16x16x32_bf16(af[mi], bfv[ni], acc[mi][ni], 0, 0, 0);
    }
    __syncthreads();
  }

  if (MODE == 2 && bcol >= 1024) {
    // v half: write transposed into vT (b,h,64,4096)
#pragma unroll
    for (int mi = 0; mi < 4; ++mi) {
#pragma unroll
      for (int ni = 0; ni < 4; ++ni) {
        int vcol = bcol - 1024 + wc * 64 + ni * 16 + l16;  // 0..1023
        int h = vcol >> 6, hd = vcol & 63;
        int row0 = brow + wr * 64 + mi * 16 + lg * 4;
        int bb = row0 >> 12, pos = row0 & 4095;
        u16x4 o4;
#pragma unroll
        for (int j = 0; j < 4; ++j) o4[j] = f2b(acc[mi][ni][j]);
        *(u16x4*)(C2 + ((size_t)((bb * 16 + h) * 64 + hd)) * 4096 + pos) = o4;
      }
    }
    return;
  }
#pragma unroll
  for (int mi = 0; mi < 4; ++mi) {
#pragma unroll
    for (int ni = 0; ni < 4; ++ni) {
#pragma unroll
      for (int j = 0; j < 4; ++j) {
        size_t row = (size_t)brow + wr * 64 + mi * 16 + lg * 4 + j;
        int col = bcol + wc * 64 + ni * 16 + l16;
        float v = acc[mi][ni][j] * oscale;
        if (MODE == 1) {
          v += bias[col];
          __builtin_nontemporal_store(v, (float*)C + row * ldc + col);
        } else {
          ((u16t*)C)[row * ldc + col] = f2b(v);
        }
      }
    }
  }
}

// ---------------- fused attention (swapped-QK^T: S^T = K @ Q^T) ----------------
// q16 pre-scaled by d^-0.5. Lane holds S[q=l16][kv=kb*16+lg*4+j].
// Counted-vmcnt barrier: the 8 NT pre-stores stay in flight across the
// barrier (only stage loads + LDS are drained) so write BW flows continuously.
__global__ __launch_bounds__(256) void k_attn(const u16t* __restrict__ k16,
                                              const u16t* __restrict__ vT16,
                                              const u16t* __restrict__ q16,
                                              const float* __restrict__ biasf,
                                              const int* __restrict__ mask,
                                              float* __restrict__ pre,
                                              u16t* __restrict__ O16) {
  __shared__ u16t Ks[2][128 * 64];   // [kv 128][hd 64] swizzled
  __shared__ u16t Vs[2][64 * 128];   // [hd 64][kv 128] swizzled
  __shared__ u16t Ps[4 * 16 * 128];  // per-wave P tile [q 16][kv 128] swizzled

  const int tid = threadIdx.x;
  const int lane = tid & 63, wid = tid >> 6;
  const int l16 = lane & 15, lg = lane >> 4;
  // XCD swizzle: w = (g%8)*64 + g/8 ; nb fastest so same (b,h) groups stay on one XCD
  const int g = blockIdx.x;
  const int w = (g & 7) * 64 + (g >> 3);
  const int nb = w & 15, hb = w >> 4;
  const int h = hb & 15, b = hb >> 4;
  const int qrow0 = nb * 64 + wid * 16;

  bf16x8 aq0, aq1;
  {
    const u16t* qp = q16 + (size_t)(b * 1024 + qrow0 + l16) * 1024 + h * 64 + lg * 8;
    aq0 = *(const bf16x8*)(qp);
    aq1 = *(const bf16x8*)(qp + 32);
  }
  const bool qm = mask[b * 1024 + qrow0 + l16] != 0;

  float mrow = -INFF, lsum = 0.f;
  f32x4 o[4] = {};

  const u16t* kbase = k16 + (size_t)b * 4096 * 1024 + (size_t)h * 64;
  const u16t* vbase = vT16 + (size_t)(b * 16 + h) * 64 * 4096;
  float* prerow = pre + (size_t)((b * 16 + h) * 1024 + qrow0 + l16) * 4096;  // this lane's q row
  const float* biasb = biasf + b * 4096;
  u16t* Pw = &Ps[wid * 2048];
  char* Pwb = (char*)Pw + l16 * 256;      // this lane's P row base (bytes)
  const int pswz = (l16 & 7) << 4;        // row-XOR swizzle

  auto stage = [&](int bufi, int kv0s) {
    u16t* Kb = &Ks[bufi][wid * 2048];
    u16t* Vb = &Vs[bufi][wid * 2048];
#pragma unroll
    for (int it = 0; it < 4; ++it) {
      int row = wid * 32 + it * 8 + (lane >> 3);
      int ch = (lane & 7) ^ (row & 7);
      gload16(kbase + (size_t)(kv0s + row) * 1024 + ch * 8, Kb + it * 512);
    }
#pragma unroll
    for (int it = 0; it < 4; ++it) {
      int row = wid * 16 + it * 4 + (lane >> 4);
      int ch = (lane & 15) ^ (row & 7);
      gload16(vbase + (size_t)row * 4096 + kv0s + ch * 8, Vb + it * 512);
    }
  };

  int cur = 0;
  stage(0, 0);
  __syncthreads();

  for (int t = 0; t < 32; ++t) {
    if (t + 1 < 32) stage(cur ^ 1, (t + 1) * 128);  // prefetch: FIRST vmem ops this iter
    asm volatile("" ::: "memory");                  // pin stage loads before later vmem
    const u16t* Kc = &Ks[cur][0];
    const u16t* Vc = &Vs[cur][0];
    const int kv0 = t * 128;

    // S^T = K @ Q^T : lane gets S[q=l16][kv=kb*16+lg*4+j] (already d^-0.5 scaled)
    f32x4 s[8];
#pragma unroll
    for (int kb = 0; kb < 8; ++kb) {
      f32x4 acc = {0.f, 0.f, 0.f, 0.f};
      int row = kb * 16 + l16;
      bf16x8 bk0 = *(const bf16x8*)(&Kc[row * 64 + ((lg ^ (row & 7)) << 3)]);
      bf16x8 bk1 = *(const bf16x8*)(&Kc[row * 64 + (((4 + lg) ^ (row & 7)) << 3)]);
      acc = __builtin_amdgcn_mfma_f32_16x16x32_bf16(bk0, aq0, acc, 0, 0, 0);
      acc = __builtin_amdgcn_mfma_f32_16x16x32_bf16(bk1, aq1, acc, 0, 0, 0);
      s[kb] = acc;
    }

    // vectorized pre-store (NT, issued last among vmem), bias add, row-max
    float tmax = -INFF;
#pragma unroll
    for (int kb = 0; kb < 8; ++kb) {
      const int colb = kv0 + kb * 16 + lg * 4;   // 4 | 1024 => same doc for j=0..3
      __builtin_nontemporal_store(s[kb], (f32x4*)(prerow + colb));
      f32x4 bv = *(const f32x4*)(biasb + colb);
#pragma unroll
      for (int j = 0; j < 4; ++j) {
        float t2 = s[kb][j] + bv[j];   // masked col: bv=-inf -> t2=-inf
        if (!qm) t2 = 0.f;
        if (t2 == 0.f) t2 = -INFF;     // faithful zero->-inf
        s[kb][j] = t2;
        tmax = fmaxf(tmax, t2);
      }
    }
    tmax = fmaxf(tmax, __shfl_xor(tmax, 16, 64));
    tmax = fmaxf(tmax, __shfl_xor(tmax, 32, 64));
    const float mold = mrow;
    const float mn = fmaxf(mold, tmax);
    const bool nochange = __all(mn == mold);
    mrow = mn;

    // P = exp(t - m) -> 8B LDS writes in A-frag layout [q=l16][kv]
    float psum = 0.f;
#pragma unroll
    for (int kb = 0; kb < 8; ++kb) {
      bf16x4 pb;
#pragma unroll
      for (int j = 0; j < 4; ++j) {
        float p = (mn == -INFF) ? 0.f : __expf(s[kb][j] - mn);
        psum += p;
        pb[j] = (__bf16)p;
      }
      *(bf16x4*)(Pwb + ((kb * 32 + lg * 8) ^ pswz)) = pb;
    }
    asm volatile("" ::: "memory");
    psum += __shfl_xor(psum, 16, 64);
    psum += __shfl_xor(psum, 32, 64);

    if (nochange) {
      lsum += psum;                      // fs == 1 for every lane: skip rescale
    } else {
      const float fs = (mn == -INFF) ? 0.f : __expf(mold - mn);
      lsum = lsum * fs + psum;
      float fsj[4];
#pragma unroll
      for (int j = 0; j < 4; ++j) fsj[j] = __shfl(fs, lg * 4 + j, 64);
#pragma unroll
      for (int ni = 0; ni < 4; ++ni)
#pragma unroll
        for (int j = 0; j < 4; ++j) o[ni][j] *= fsj[j];
    }

    // O += P @ V
#pragma unroll
    for (int kk2 = 0; kk2 < 4; ++kk2) {
      bf16x8 pa = *(const bf16x8*)(Pwb + ((kk2 * 64 + lg * 16) ^ pswz));
#pragma unroll
      for (int ni = 0; ni < 4; ++ni) {
        int vrow = ni * 16 + l16;
        bf16x8 vb = *(const bf16x8*)(&Vc[vrow * 128 + (((kk2 * 4 + lg) ^ (vrow & 7)) << 3)]);
        o[ni] = __builtin_amdgcn_mfma_f32_16x16x32_bf16(pa, vb, o[ni], 0, 0, 0);
      }
    }

    // counted-vmcnt barrier: drain stage loads (+bias loads) and LDS ops,
    // but leave the 8 NT pre-stores (last-issued vmem) in flight.
    asm volatile("s_waitcnt vmcnt(8) lgkmcnt(0)" ::: "memory");
    __builtin_amdgcn_sched_barrier(0);
    __builtin_amdgcn_s_barrier();
    __builtin_amdgcn_sched_barrier(0);
    cur ^= 1;
  }

  float lsj[4];
#pragma unroll
  for (int j = 0; j < 4; ++j) lsj[j] = __shfl(lsum, lg * 4 + j, 64);
#pragma unroll
  for (int ni = 0; ni < 4; ++ni) {
#pragma unroll
    for (int j = 0; j < 4; ++j) {
      size_t row = (size_t)b * 1024 + qrow0 + lg * 4 + j;
      int col = h * 64 + ni * 16 + l16;
      O16[row * 1024 + col] = f2b(o[ni][j] / lsj[j]);
    }
  }
}

extern "C" void kernel_launch(void* const* d_in, const int* in_sizes, int n_in,
                              void* d_out, int out_size, void* d_ws, size_t ws_size,
                              hipStream_t stream) {
  const float* x = (const float*)d_in[0];
  const float* ctx = (const float*)d_in[1];
  const float* dsim = (const float*)d_in[2];
  const int* mask = (const int*)d_in[3];
  const int* cmask = (const int*)d_in[4];
  const float* Wq = (const float*)d_in[5];
  const float* Wkv = (const float*)d_in[6];
  const float* Wout = (const float*)d_in[7];
  const float* bout = (const float*)d_in[8];
  const float* beta = (const float*)d_in[9];

  char* ws = (char*)d_ws;
  u16t* q16 = (u16t*)(ws + (0ull << 20));     //  4 MiB (2048x1024), pre-scaled by d^-0.5
  u16t* k16 = (u16t*)(ws + (4ull << 20));     // 16 MiB (8192x1024) k half, compact
  u16t* vT16 = (u16t*)(ws + (36ull << 20));   // 16 MiB (2,16,64,4096)
  u16t* O16 = (u16t*)(ws + (52ull << 20));    //  4 MiB (2048x1024)
  u16t* x16 = (u16t*)(ws + (56ull << 20));    //  4 MiB
  u16t* ctx16 = (u16t*)(ws + (60ull << 20));  // 16 MiB
  u16t* WqT = (u16t*)(ws + (76ull << 20));    //  2 MiB
  u16t* WkvT = (u16t*)(ws + (78ull << 20));   //  4 MiB
  u16t* WoutT = (u16t*)(ws + (82ull << 20));  //  2 MiB
  float* biasf = (float*)(ws + (84ull << 20)); // 32 KiB (2 x 4096 f32)

  float* outp = (float*)d_out;
  float* pre = outp + (size_t)2 * 1024 * 1024;

  // fused cvt(x), cvt(ctx), bias table
  k_prep<<<10248, 256, 0, stream>>>(x, ctx, x16, ctx16, cmask, dsim, beta, biasf);
  // fused 3x weight transpose
  k_transpose_w3<<<dim3(64, 16), 256, 0, stream>>>(Wq, Wkv, Wout, WqT, WkvT, WoutT);

  // q = (x @ Wq) * d^-0.5   (2048x1024) bf16  (scale fold is exact: 2^-5)
  k_gemm_bt<0><<<128, 256, 0, stream>>>(x16, WqT, (void*)q16, nullptr, nullptr, 0.03125f, 1024, 1024, 1024, 1024, 8);
  // kv GEMM: k half -> k16 (compact), v half -> vT16 (transposed per head)
  k_gemm_bt<2><<<1024, 256, 0, stream>>>(ctx16, WkvT, (void*)k16, vT16, nullptr, 1.0f, 1024, 1024, 1024, 1024, 16);
  // fused QK^T + pre-store + softmax + PV
  k_attn<<<512, 256, 0, stream>>>(k16, vT16, q16, biasf, mask, pre, O16);
  // out = O @ Wout + bout  (f32)
  k_gemm_bt<1><<<128, 256, 0, stream>>>(O16, WoutT, d_out, nullptr, bout, 1.0f, 1024, 1024, 1024, 1024, 8);
}